// Round 13
// baseline (4901.641 us; speedup 1.0000x reference)
//
#include <hip/hip_runtime.h>
#include <math.h>

#define SEQ   512
#define BATCH 256
#define IDIM  256
#define HDIM  512
#define ODIM  256
#define NGROUP 16   // batch groups (bi), 16 rows each
#define GBLK   16   // blocks per group (gj), 32 h-cols each

#define OUT_ELEMS ((size_t)SEQ * BATCH * ODIM)
#define HF_OFF OUT_ELEMS
#define CF_OFF (OUT_ELEMS + (size_t)BATCH * HDIM)

// h exchange: 3-buffer ring, each buf = [2 planes][256 rows][256 u32 fp16-pair words]
#define HPLANE 65536u
#define BUFW   131072u
#define SENT   0x7F7F7F7Fu        // fp16 NaN|NaN — unreachable for |h|<1 payload
#define SPIN_TIMEOUT 5000000ull   // 50 ms per poll: diagnostic bail, no 600s hang class

#define H_SCALE 4096.0f
#define H_INV   2.44140625e-4f   // 2^-12
#define HMIN    6.104e-5f        // fp16 min normal
#define ZW      390              // u32 row stride of z planes (bank-spread)

typedef __attribute__((ext_vector_type(8))) _Float16 half8;
typedef __attribute__((ext_vector_type(4))) float f32x4;
typedef __attribute__((ext_vector_type(4))) unsigned int uint4v;

__device__ __forceinline__ unsigned short hbits(_Float16 h) {
  return __builtin_bit_cast(unsigned short, h);
}

__device__ __forceinline__ f32x4 mfma_h(half8 a, half8 b, f32x4 c) {
  return __builtin_amdgcn_mfma_f32_16x16x32_f16(a, b, c, 0, 0, 0);
}

// ---- system-coherent (cache-bypassing) accessors ----
__device__ __forceinline__ void st_sys_u32(unsigned int* p, unsigned int d) {
  asm volatile("global_store_dword %0, %1, off sc0 sc1"
               : : "v"((unsigned long long)p), "v"(d) : "memory");
}

// Two 64B plane slices (hi, lo) in one burst, single vmcnt(0).
__device__ __forceinline__ void ld_2x64_sys(const unsigned int* p0, const unsigned int* p1,
                                            uint4v a[4], uint4v b[4]) {
  asm volatile(
      "global_load_dwordx4 %0, %8, off sc0 sc1\n\t"
      "global_load_dwordx4 %1, %8, off offset:16 sc0 sc1\n\t"
      "global_load_dwordx4 %2, %8, off offset:32 sc0 sc1\n\t"
      "global_load_dwordx4 %3, %8, off offset:48 sc0 sc1\n\t"
      "global_load_dwordx4 %4, %9, off sc0 sc1\n\t"
      "global_load_dwordx4 %5, %9, off offset:16 sc0 sc1\n\t"
      "global_load_dwordx4 %6, %9, off offset:32 sc0 sc1\n\t"
      "global_load_dwordx4 %7, %9, off offset:48 sc0 sc1\n\t"
      "s_waitcnt vmcnt(0)"
      : "=&v"(a[0]), "=&v"(a[1]), "=&v"(a[2]), "=&v"(a[3]),
        "=&v"(b[0]), "=&v"(b[1]), "=&v"(b[2]), "=&v"(b[3])
      : "v"((unsigned long long)p0), "v"((unsigned long long)p1)
      : "memory");
}

// Poll the 32-word slice until every word is non-sentinel (32-bit stores are
// atomic; each word valid the moment it is non-sentinel). Tight loop.
__device__ __forceinline__ void poll_slab(const unsigned int* p0, const unsigned int* p1,
                                          uint4v a[4], uint4v b[4]) {
  unsigned long long t0 = __builtin_amdgcn_s_memrealtime();
  for (;;) {
    ld_2x64_sys(p0, p1, a, b);
    unsigned int bad = 0;
#pragma unroll
    for (int j = 0; j < 4; ++j)
#pragma unroll
      for (int e = 0; e < 4; ++e) {
        bad |= (a[j][e] == SENT);
        bad |= (b[j][e] == SENT);
      }
    if (!bad) return;
    if (__builtin_amdgcn_s_memrealtime() - t0 > SPIN_TIMEOUT) return;  // diagnostic bail
  }
}

// Scaled split-2: v = hi + lo*2^-12 + O(2^-23 * v).
__device__ __forceinline__ void split_f(float f, _Float16 &hi, _Float16 &lo) {
  _Float16 a = (_Float16)0.f;
  if (fabsf(f) >= HMIN) a = (_Float16)f;
  float f1 = (float)a;
  hi = a;
  lo = (_Float16)((f - f1) * H_SCALE);
}

__device__ __forceinline__ float sigm(float x)   { return 1.f / (1.f + expf(-x)); }
__device__ __forceinline__ float tanh_f(float x) { return 1.f - 2.f / (expf(2.f * x) + 1.f); }

// Protocol v3 (round-9 proven): sentinel-validated payload, 3-buffer ring.
// Pipeline trim: x[t+1] staged in the publish-propagation shadow.
// grid=256, block=256=4 waves (wave w = gate type w for its 32 h-cols).
__global__ void __launch_bounds__(256, 1)
lstm_mfma(const float* __restrict__ xs,
          const float* __restrict__ Wih,
          const float* __restrict__ Whh,
          const float* __restrict__ bih,
          const float* __restrict__ bhh,
          const float* __restrict__ Wfc,
          const float* __restrict__ bfc,
          float* __restrict__ out,
          unsigned int* __restrict__ hb)   // 3 x BUFW ring
{
  const int tid = threadIdx.x;
  const int w   = tid >> 6;
  const int l   = tid & 63;
  const int lr  = l & 15;     // A row / B,D col
  const int lk  = l >> 4;     // k subgroup

  const int bi  = blockIdx.x & (NGROUP - 1);
  const int gj  = blockIdx.x / NGROUP;
  const int r0  = bi * 16;
  const int hc0 = gj * 32;
  const int oc0 = gj * 16;    // out-col base == h pair-word base

  // ---- persistent fp16 split-2 weight fragments, merged K = [h 16 tiles | x 8 tiles] ----
  half8 wz1[24][2], wz2[24][2];
#pragma unroll
  for (int kk = 0; kk < 24; ++kk)
#pragma unroll
    for (int nt = 0; nt < 2; ++nt) {
      int g = w * HDIM + hc0 + nt * 16 + lr;
      const float* src = (kk < 16)
          ? (Whh + (size_t)g * HDIM + kk * 32 + lk * 8)
          : (Wih + (size_t)g * IDIM + (kk - 16) * 32 + lk * 8);
      const f32x4 va = *(const f32x4*)src;
      const f32x4 vb = *(const f32x4*)(src + 4);
#pragma unroll
      for (int j = 0; j < 4; ++j) { _Float16 h, lo; split_f(va[j], h, lo); wz1[kk][nt][j] = h; wz2[kk][nt][j] = lo; }
#pragma unroll
      for (int j = 0; j < 4; ++j) { _Float16 h, lo; split_f(vb[j], h, lo); wz1[kk][nt][4 + j] = h; wz2[kk][nt][4 + j] = lo; }
    }
  half8 wfc1[4];   // FC weight hi-level only (error non-recurrent)
#pragma unroll
  for (int q = 0; q < 4; ++q) {
    const float* src = Wfc + (size_t)(oc0 + lr) * HDIM + (w * 4 + q) * 32 + lk * 8;
#pragma unroll
    for (int j = 0; j < 8; ++j) { _Float16 h, lo; split_f(src[j], h, lo); wfc1[q][j] = h; }
  }
  float gb[2];
#pragma unroll
  for (int nt = 0; nt < 2; ++nt) {
    int g = w * HDIM + hc0 + nt * 16 + lr;
    gb[nt] = bih[g] + bhh[g];
  }

  const int rrow = tid >> 4;
  const int rcp  = tid & 15;
  const float fcb = bfc[oc0 + rcp];
  const unsigned int wi_row = (unsigned)(r0 + rrow) * 256u + (unsigned)(oc0 + rcp);

  __shared__ unsigned int z1[16][ZW];   // hi plane: [h 256 u32 | x 128 u32] fp16 pairs
  __shared__ unsigned int z2[16][ZW];   // lo plane (2^12-scaled residual)
  __shared__ float lds_g[4][16][32];
  __shared__ float lds_fc[4][16][16];
  __shared__ float lds_c[16][32];

  lds_c[rrow][2 * rcp]     = 0.f;
  lds_c[rrow][2 * rcp + 1] = 0.f;

  const int srow = tid & 15;   // staging row
  const int schk = tid >> 4;   // staging chunk (== producer gj of that slice)

  // ---- preloop: stage x[0]; zero h cols (h0 = 0) ----
  {
    const float* xt = xs + (size_t)(r0 + srow) * IDIM + schk * 16;
#pragma unroll
    for (int v4 = 0; v4 < 4; ++v4) {
      f32x4 xv = *(const f32x4*)(xt + 4 * v4);
      _Float16 h0, l0, h1, l1, h2, l2, h3, l3;
      split_f(xv[0], h0, l0); split_f(xv[1], h1, l1);
      split_f(xv[2], h2, l2); split_f(xv[3], h3, l3);
      int c = 256 + schk * 8 + 2 * v4;
      z1[srow][c]     = (unsigned int)hbits(h0) | ((unsigned int)hbits(h1) << 16);
      z2[srow][c]     = (unsigned int)hbits(l0) | ((unsigned int)hbits(l1) << 16);
      z1[srow][c + 1] = (unsigned int)hbits(h2) | ((unsigned int)hbits(h3) << 16);
      z2[srow][c + 1] = (unsigned int)hbits(l2) | ((unsigned int)hbits(l3) << 16);
    }
#pragma unroll
    for (int i = 0; i < 16; ++i) {
      z1[srow][schk * 16 + i] = 0u;
      z2[srow][schk * 16 + i] = 0u;
    }
  }
  __syncthreads();

  // ring: at step t read pR (h[t-1]), write pW (h[t]), sentinel pS (future h[t+1])
  unsigned int* pR = hb + 2u * BUFW;
  unsigned int* pW = hb;
  unsigned int* pS = hb + BUFW;

#pragma unroll 1
  for (int t = 0; t < SEQ; ++t) {
    // ---- x-part of gates first (x staged last iter): overlaps producers' latency ----
    f32x4 ga0 = {gb[0], gb[0], gb[0], gb[0]};
    f32x4 ga1 = {gb[1], gb[1], gb[1], gb[1]};
    f32x4 gl0 = {0.f, 0.f, 0.f, 0.f};
    f32x4 gl1 = {0.f, 0.f, 0.f, 0.f};
    const unsigned short* zr1 = (const unsigned short*)&z1[lr][0];
    const unsigned short* zr2 = (const unsigned short*)&z2[lr][0];
#pragma unroll
    for (int kk = 16; kk < 24; ++kk) {
      half8 a1 = *(const half8*)(zr1 + kk * 32 + lk * 8);
      half8 a2 = *(const half8*)(zr2 + kk * 32 + lk * 8);
      ga0 = mfma_h(a1, wz1[kk][0], ga0);
      gl0 = mfma_h(a2, wz1[kk][0], gl0);
      gl0 = mfma_h(a1, wz2[kk][0], gl0);
      ga1 = mfma_h(a1, wz1[kk][1], ga1);
      gl1 = mfma_h(a2, wz1[kk][1], gl1);
      gl1 = mfma_h(a1, wz2[kk][1], gl1);
    }

    // ---- poll + stage h[t-1]; sentinel own slice of pS ----
    if (t > 0) {
      const unsigned int* p1 = pR + (unsigned)(r0 + srow) * 256u + (unsigned)(schk * 16);
      uint4v a[4], b[4];
      poll_slab(p1, p1 + HPLANE, a, b);
#pragma unroll
      for (int j = 0; j < 4; ++j)
#pragma unroll
        for (int e = 0; e < 4; ++e) {
          z1[srow][schk * 16 + 4 * j + e] = a[j][e];
          z2[srow][schk * 16 + 4 * j + e] = b[j][e];
        }
    }
    // sentinel the words this thread will publish h[t+1] into (ordered before
    // the h[t] publish by the vmcnt(0) below; 3-buffer staleness proof as r9)
    st_sys_u32(pS + wi_row,          SENT);
    st_sys_u32(pS + HPLANE + wi_row, SENT);
    __syncthreads();   // sync2: h staged

    // ---- h-part of gates ----
    if (t > 0) {
#pragma unroll
      for (int kk = 0; kk < 16; ++kk) {
        half8 a1 = *(const half8*)(zr1 + kk * 32 + lk * 8);
        half8 a2 = *(const half8*)(zr2 + kk * 32 + lk * 8);
        ga0 = mfma_h(a1, wz1[kk][0], ga0);
        gl0 = mfma_h(a2, wz1[kk][0], gl0);
        gl0 = mfma_h(a1, wz2[kk][0], gl0);
        ga1 = mfma_h(a1, wz1[kk][1], ga1);
        gl1 = mfma_h(a2, wz1[kk][1], gl1);
        gl1 = mfma_h(a1, wz2[kk][1], gl1);
      }
    }

    // ---- FC head on h[t-1] (K-quarter per wave) ----
    f32x4 f1a = {0.f, 0.f, 0.f, 0.f};
    f32x4 f2a = {0.f, 0.f, 0.f, 0.f};
    if (t > 0) {
#pragma unroll
      for (int q = 0; q < 4; ++q) {
        int kk = w * 4 + q;
        half8 a1 = *(const half8*)(zr1 + kk * 32 + lk * 8);
        half8 a2 = *(const half8*)(zr2 + kk * 32 + lk * 8);
        f1a = mfma_h(a1, wfc1[q], f1a);
        f2a = mfma_h(a2, wfc1[q], f2a);
      }
    }

    // ---- fold + exchange ----
#pragma unroll
    for (int j = 0; j < 4; ++j) {
      lds_g[w][lk * 4 + j][lr]      = ga0[j] + gl0[j] * H_INV;
      lds_g[w][lk * 4 + j][16 + lr] = ga1[j] + gl1[j] * H_INV;
      lds_fc[w][lk * 4 + j][lr]     = f1a[j] + f2a[j] * H_INV;
    }
    __syncthreads();   // sync3

    // ---- recombine ----
    float hn[2], cn[2];
#pragma unroll
    for (int q = 0; q < 2; ++q) {
      int c = 2 * rcp + q;
      float ig = sigm(lds_g[0][rrow][c]);
      float fg = sigm(lds_g[1][rrow][c]);
      float gg = tanh_f(lds_g[2][rrow][c]);
      float og = sigm(lds_g[3][rrow][c]);
      float cc = fg * lds_c[rrow][c] + ig * gg;
      lds_c[rrow][c] = cc;
      cn[q] = cc;
      hn[q] = og * tanh_f(cc);
    }

    // ---- drain (orders sentinels), publish h[t]; no post-publish drain/sync ----
    asm volatile("s_waitcnt vmcnt(0)" ::: "memory");
    {
      _Float16 h0h, h0l, h1h, h1l;
      split_f(hn[0], h0h, h0l);
      split_f(hn[1], h1h, h1l);
      unsigned int hiw = (unsigned int)hbits(h0h) | ((unsigned int)hbits(h1h) << 16);
      unsigned int low = (unsigned int)hbits(h0l) | ((unsigned int)hbits(h1l) << 16);
      st_sys_u32(pW + wi_row,          hiw);
      st_sys_u32(pW + HPLANE + wi_row, low);
    }

    // ---- out stores + x[t+1] staging: both in the publish-propagation shadow ----
    if (t > 0) {
      float o = lds_fc[0][rrow][rcp] + lds_fc[1][rrow][rcp]
              + lds_fc[2][rrow][rcp] + lds_fc[3][rrow][rcp] + fcb;
      out[((size_t)(t - 1) * BATCH + (r0 + rrow)) * ODIM + oc0 + rcp] = o;
    }
    if (t == SEQ - 1) {
#pragma unroll
      for (int q = 0; q < 2; ++q) {
        size_t hi_ = (size_t)(r0 + rrow) * HDIM + hc0 + 2 * rcp + q;
        out[HF_OFF + hi_] = hn[q];
        out[CF_OFF + hi_] = cn[q];
      }
    }
    if (t + 1 < SEQ) {
      const float* xt = xs + (size_t)(t + 1) * BATCH * IDIM
                      + (size_t)(r0 + srow) * IDIM + schk * 16;
#pragma unroll
      for (int v4 = 0; v4 < 4; ++v4) {
        f32x4 xv = *(const f32x4*)(xt + 4 * v4);
        _Float16 h0, l0, h1, l1, h2, l2, h3, l3;
        split_f(xv[0], h0, l0); split_f(xv[1], h1, l1);
        split_f(xv[2], h2, l2); split_f(xv[3], h3, l3);
        int c = 256 + schk * 8 + 2 * v4;
        z1[srow][c]     = (unsigned int)hbits(h0) | ((unsigned int)hbits(h1) << 16);
        z2[srow][c]     = (unsigned int)hbits(l0) | ((unsigned int)hbits(l1) << 16);
        z1[srow][c + 1] = (unsigned int)hbits(h2) | ((unsigned int)hbits(h3) << 16);
        z2[srow][c + 1] = (unsigned int)hbits(l2) | ((unsigned int)hbits(l3) << 16);
      }
    }
    __syncthreads();   // sync1: x[t+1] staged; prev-step reads all closed

    // rotate ring
    unsigned int* tmp = pR; pR = pW; pW = pS; pS = tmp;
  }

  // ---- tail: out[SEQ-1] from h[SEQ-1] (pR now = buf[(SEQ-1)%3]) ----
  {
    const unsigned int* p1 = pR + (unsigned)(r0 + srow) * 256u + (unsigned)(schk * 16);
    uint4v a[4], b[4];
    poll_slab(p1, p1 + HPLANE, a, b);
#pragma unroll
    for (int j = 0; j < 4; ++j)
#pragma unroll
      for (int e = 0; e < 4; ++e) {
        z1[srow][schk * 16 + 4 * j + e] = a[j][e];
        z2[srow][schk * 16 + 4 * j + e] = b[j][e];
      }
    __syncthreads();
    f32x4 f1a = {0.f, 0.f, 0.f, 0.f};
    f32x4 f2a = {0.f, 0.f, 0.f, 0.f};
    const unsigned short* zr1 = (const unsigned short*)&z1[lr][0];
    const unsigned short* zr2 = (const unsigned short*)&z2[lr][0];
#pragma unroll
    for (int q = 0; q < 4; ++q) {
      int kk = w * 4 + q;
      half8 a1 = *(const half8*)(zr1 + kk * 32 + lk * 8);
      half8 a2 = *(const half8*)(zr2 + kk * 32 + lk * 8);
      f1a = mfma_h(a1, wfc1[q], f1a);
      f2a = mfma_h(a2, wfc1[q], f2a);
    }
#pragma unroll
    for (int j = 0; j < 4; ++j)
      lds_fc[w][lk * 4 + j][lr] = f1a[j] + f2a[j] * H_INV;
    __syncthreads();
    float o = lds_fc[0][rrow][rcp] + lds_fc[1][rrow][rcp]
            + lds_fc[2][rrow][rcp] + lds_fc[3][rrow][rcp] + fcb;
    out[((size_t)(SEQ - 1) * BATCH + (r0 + rrow)) * ODIM + oc0 + rcp] = o;
  }
}

extern "C" void kernel_launch(void* const* d_in, const int* in_sizes, int n_in,
                              void* d_out, int out_size, void* d_ws, size_t ws_size,
                              hipStream_t stream)
{
  const float* xs  = (const float*)d_in[0];
  const float* wih = (const float*)d_in[1];
  const float* whh = (const float*)d_in[2];
  const float* bi_ = (const float*)d_in[3];
  const float* bh_ = (const float*)d_in[4];
  const float* wfc = (const float*)d_in[5];
  const float* bf_ = (const float*)d_in[6];
  float* out = (float*)d_out;

  unsigned int* hb = (unsigned int*)d_ws;   // 1.5 MB: 3-buffer h ring

  // sentinel-fill the whole ring every call (0x7F7F7F7F per word)
  hipMemsetAsync(hb, 0x7F, (size_t)3 * BUFW * 4, stream);

  lstm_mfma<<<dim3(NGROUP * GBLK), dim3(256), 0, stream>>>(
      xs, wih, whh, bi_, bh_, wfc, bf_, out, hb);
}